// Round 17
// baseline (235.805 us; speedup 1.0000x reference)
//
#include <hip/hip_runtime.h>
#include <hip/hip_bf16.h>
#include <stdint.h>

typedef __attribute__((ext_vector_type(8))) short bf16x8;
typedef __attribute__((ext_vector_type(4))) float f32x4;
typedef __attribute__((ext_vector_type(16))) float f32x16;
typedef __attribute__((ext_vector_type(4))) unsigned int u32x4;

#define B_    2
#define L_    2048
#define DIM_  2048
#define NH_   32
#define NKV_  8
#define HD_   64
#define KVD_  512          // NKV_*HD_
#define CLOG_ 0.1803368801111244f   // SCALE * log2(e), folded into Q in attn prologue

__device__ __forceinline__ unsigned short f2bf(float f) {
  unsigned u = __float_as_uint(f);
  u += 0x7fff + ((u >> 16) & 1);          // round-to-nearest-even
  return (unsigned short)(u >> 16);
}
// hw packed f32->bf16 (RNE), 1 VALU op
__device__ __forceinline__ unsigned cvtpk(float lo, float hi_) {
  unsigned r;
  asm("v_cvt_pk_bf16_f32 %0, %1, %2" : "=v"(r) : "v"(lo), "v"(hi_));
  return r;
}
__device__ __forceinline__ float bf2f(unsigned short h) {
  return __uint_as_float(((unsigned)h) << 16);
}
// v_permlane32_swap_b32: a' = [a_lo | b_lo], b' = [a_hi | b_hi]
__device__ __forceinline__ void plswap2(unsigned &a, unsigned &b, int hi) {
#if __has_builtin(__builtin_amdgcn_permlane32_swap)
  auto r = __builtin_amdgcn_permlane32_swap(a, b, false, false);
  a = (unsigned)r[0]; b = (unsigned)r[1];
#else
  unsigned xa = (unsigned)__shfl_xor((int)a, 32);
  unsigned xb = (unsigned)__shfl_xor((int)b, 32);
  unsigned na = hi ? xb : a, nb = hi ? b : xa;
  a = na; b = nb;
#endif
}

#define GLDS16(gsrc, ldst) __builtin_amdgcn_global_load_lds( \
    (const __attribute__((address_space(1))) unsigned int*)(gsrc), \
    (__attribute__((address_space(3))) unsigned int*)(ldst), 16, 0, 0)

// ---------------- fused f32 -> bf16 convert of all 5 tensors ----------------
__global__ void cvt_all(const float* __restrict__ x,  const float* __restrict__ wq,
                        const float* __restrict__ wk, const float* __restrict__ wv,
                        const float* __restrict__ wo,
                        unsigned short* __restrict__ xb,  unsigned short* __restrict__ wqb,
                        unsigned short* __restrict__ wkb, unsigned short* __restrict__ wvb,
                        unsigned short* __restrict__ wob) {
  int i = blockIdx.x * blockDim.x + threadIdx.x;
  const float* src; unsigned short* dst; int off;
  if (i < 2097152)      { src = x;  dst = xb;  off = i; }
  else if (i < 3145728) { src = wq; dst = wqb; off = i - 2097152; }
  else if (i < 3407872) { src = wk; dst = wkb; off = i - 3145728; }
  else if (i < 3670016) { src = wv; dst = wvb; off = i - 3407872; }
  else                  { src = wo; dst = wob; off = i - 3670016; }
  float4 v = reinterpret_cast<const float4*>(src)[off];
  ushort4 o;
  o.x = f2bf(v.x); o.y = f2bf(v.y); o.z = f2bf(v.z); o.w = f2bf(v.w);
  reinterpret_cast<ushort4*>(dst)[off] = o;
}

// ===== 128x128 GEMM core: counted-vmcnt double-buffer, BK=32 (32 KB LDS) ====
// Round-15 verified best (total 212.6). Per K-tile: STAGE(next: 4 gload_lds);
// vmcnt(4); s_barrier; 8 swizzled ds_read_b128 + 16 MFMA (setprio); lgkmcnt(0);
// s_barrier. 64-byte rows: swizzle slot g ^= (row>>1)&3 (16B slots; 2-way
// bank aliasing = free), same involution on staging source and ds_read.
// OUTMODE: 0 = bf16 C[M,N], 1 = f32 C[M,N], 2 = V-transposed Vt[B,KV,D,L],
//          3 = bf16 K with FUSED RoPE (pair partner via shfl_xor(1))
template<int OUTMODE>
__device__ __forceinline__ void gemm128_core(
    const unsigned short* __restrict__ A,
    const unsigned short* __restrict__ W,
    void* __restrict__ C, int N, int K, int m0, int n0,
    unsigned short (*As)[128 * 32], unsigned short (*Bs)[128 * 32],
    const float* __restrict__ fc, const float* __restrict__ fs)
{
  const int tid = threadIdx.x;
  const int lane = tid & 63, wid = tid >> 6;
  const int wm = wid >> 1, wn = wid & 1;
  const int r = lane & 15, g = lane >> 4;
  f32x4 acc[4][4] = {};

  auto STAGE = [&](int buf, int k0) {
#pragma unroll
    for (int p = 0; p < 2; ++p) {
      int off = (p * 256 + tid) * 16;              // 0..8191
      int row = off >> 6;                          // 0..127
      int colb = (off & 63) ^ (((row >> 1) & 3) << 4);   // inverse-swizzled src
      GLDS16((const char*)A + ((size_t)(m0 + row) * K + k0) * 2 + colb,
             (char*)As[buf] + off);
      GLDS16((const char*)W + ((size_t)(n0 + row) * K + k0) * 2 + colb,
             (char*)Bs[buf] + off);
    }
  };

  const int nt = K >> 5;
  STAGE(0, 0);
  asm volatile("s_waitcnt vmcnt(0)" ::: "memory");
  __builtin_amdgcn_s_barrier();
  int cur = 0;
  for (int kt = 0; kt < nt; ++kt) {
    if (kt + 1 < nt) {
      STAGE(cur ^ 1, (kt + 1) << 5);
      asm volatile("s_waitcnt vmcnt(4)" ::: "memory");   // prior tile landed
    } else {
      asm volatile("s_waitcnt vmcnt(0)" ::: "memory");
    }
    __builtin_amdgcn_s_barrier();
    __builtin_amdgcn_sched_barrier(0);
    const char* Ab = (const char*)As[cur];
    const char* Bb = (const char*)Bs[cur];
    bf16x8 af[4], bfv[4];
#pragma unroll
    for (int i = 0; i < 4; ++i) {
      int Ra = wm * 64 + i * 16 + r;
      af[i] = *reinterpret_cast<const bf16x8*>(
          Ab + Ra * 64 + ((g ^ ((Ra >> 1) & 3)) << 4));
    }
#pragma unroll
    for (int i = 0; i < 4; ++i) {
      int Rb = wn * 64 + i * 16 + r;
      bfv[i] = *reinterpret_cast<const bf16x8*>(
          Bb + Rb * 64 + ((g ^ ((Rb >> 1) & 3)) << 4));
    }
    __builtin_amdgcn_s_setprio(1);
#pragma unroll
    for (int i = 0; i < 4; ++i)
#pragma unroll
      for (int j = 0; j < 4; ++j)
        acc[i][j] = __builtin_amdgcn_mfma_f32_16x16x32_bf16(af[i], bfv[j], acc[i][j], 0, 0, 0);
    __builtin_amdgcn_s_setprio(0);
    asm volatile("s_waitcnt lgkmcnt(0)" ::: "memory");   // reads done before overwrite
    __builtin_amdgcn_s_barrier();
    cur ^= 1;
  }

  if (OUTMODE == 2) {
#pragma unroll
    for (int i = 0; i < 4; ++i)
#pragma unroll
      for (int jf = 0; jf < 4; ++jf) {
        int col = n0 + wn * 64 + jf * 16 + r;        // 0..511
        int kvi = col >> 6, d = col & 63;
        int tok = m0 + wm * 64 + i * 16 + g * 4;     // 4 consecutive tokens
        int bb = tok >> 11, tl = tok & (L_ - 1);
        uint2 u;
        u.x = cvtpk(acc[i][jf][0], acc[i][jf][1]);
        u.y = cvtpk(acc[i][jf][2], acc[i][jf][3]);
        *reinterpret_cast<uint2*>((unsigned short*)C +
            ((size_t)((bb * NKV_ + kvi) * HD_ + d)) * L_ + tl) = u;
      }
  } else if (OUTMODE == 3) {
    // K output with fused RoPE. col = one head-dim d (4 consecutive tokens).
    // Pair partner d^1 lives in lane^1 (col = ... + r, r = lane&15).
    // even d: out = te*c - to*s ; odd d: out = te*s + to*c.
#pragma unroll
    for (int i = 0; i < 4; ++i)
#pragma unroll
      for (int jf = 0; jf < 4; ++jf) {
        int col = n0 + wn * 64 + jf * 16 + r;        // 0..511
        int pi = (col & 63) >> 1;                    // pair index within head
        int odd = col & 1;
        int tok = m0 + wm * 64 + i * 16 + g * 4;
#pragma unroll
        for (int j2 = 0; j2 < 4; ++j2) {
          float own = acc[i][jf][j2];
          float par = __shfl_xor(own, 1);
          int l = (tok + j2) & (L_ - 1);
          float c = fc[l * 32 + pi], s = fs[l * 32 + pi];
          float v = odd ? (par * s + own * c) : (own * c - par * s);
          ((unsigned short*)C)[(size_t)(tok + j2) * N + col] = f2bf(v);
        }
      }
  } else {
#pragma unroll
    for (int i = 0; i < 4; ++i)
#pragma unroll
      for (int jf = 0; jf < 4; ++jf)
#pragma unroll
        for (int j = 0; j < 4; ++j) {
          size_t row = (size_t)(m0 + wm * 64 + i * 16 + g * 4 + j);
          size_t col = (size_t)(n0 + wn * 64 + jf * 16 + r);
          float v = acc[i][jf][j];
          if (OUTMODE == 1) ((float*)C)[row * N + col] = v;
          else ((unsigned short*)C)[row * N + col] = f2bf(v);
        }
  }
}

// ---------------- out-projection / generic GEMM ----------------
template<int OUT_F32>
__global__ __launch_bounds__(256) void gemm_bt(
    const unsigned short* __restrict__ A,
    const unsigned short* __restrict__ W,
    void* __restrict__ C, int M, int N, int K)
{
  __shared__ unsigned short As[2][128 * 32];
  __shared__ unsigned short Bs[2][128 * 32];
  gemm128_core<OUT_F32 ? 1 : 0>(A, W, C, N, K, blockIdx.y * 128, blockIdx.x * 128,
                                As, Bs, nullptr, nullptr);
}

// ------- fused QKV GEMM (V written TRANSPOSED; K written with RoPE) --------
__global__ __launch_bounds__(256) void gemm_qkv(
    const unsigned short* __restrict__ A,
    const unsigned short* __restrict__ Wq,
    const unsigned short* __restrict__ Wk,
    const unsigned short* __restrict__ Wv,
    unsigned short* __restrict__ Cq,
    unsigned short* __restrict__ Ck,
    unsigned short* __restrict__ Vt,
    const float* __restrict__ fc, const float* __restrict__ fs)
{
  __shared__ unsigned short As[2][128 * 32];
  __shared__ unsigned short Bs[2][128 * 32];
  const int bx = blockIdx.x;
  const int m0 = blockIdx.y * 128;
  if (bx < 16)
    gemm128_core<0>(A, Wq, Cq, 2048, DIM_, m0, bx * 128, As, Bs, nullptr, nullptr);
  else if (bx < 20)
    gemm128_core<3>(A, Wk, Ck, 512, DIM_, m0, (bx - 16) * 128, As, Bs, fc, fs);
  else
    gemm128_core<2>(A, Wv, Vt, 512, DIM_, m0, (bx - 20) * 128, As, Bs, nullptr, nullptr);
}

// ---------------- Flash attention (round-14/15 verified: ~95 us) ------------
// 1D grid, boustrophedon snake chunk mapping; 4 waves x 32 q-rows = 128 q.
// SINGLE barrier per K-tile; Q-RoPE + scale fused into prologue;
// permlane32_swap P exchange; fixed-max log2 softmax; lane-local lrow.
__global__ __launch_bounds__(256) void attn_kernel(
    const unsigned short* __restrict__ Q,
    const unsigned short* __restrict__ K,
    const unsigned short* __restrict__ Vt,
    const float* __restrict__ fc, const float* __restrict__ fs,
    unsigned short* __restrict__ AO)
{
  __shared__ unsigned short Ks[2][64 * 64];
  __shared__ unsigned short Vs[2][64 * 64];
  const int tid = threadIdx.x;
  const int lane = tid & 63, w = tid >> 6;
  const int ql = lane & 31;
  const int hi = lane >> 5;
  const int wid = blockIdx.x;
  const int j = wid >> 6;
  const int blk = j >> 2, pos = j & 3;
  const int base = 15 - 4 * blk;                       // 15,11,7,3
  const int qt = (blk & 1) ? (base - 3 + pos) : (base - pos);
  const int bh = wid & 63;
  const int b = bh >> 5, h = bh & 31, kv = h >> 2;
  const int q0 = qt * 128;
  const int qw = q0 + w * 32;
  const int nkt = (q0 + 128) >> 6;

  // ---- Q fragments with fused RoPE + scale ----
  bf16x8 qf[4];
  {
    const unsigned short* qrow = Q + ((size_t)(b * L_ + qw + ql)) * DIM_ + h * HD_;
    const float* fcr = fc + (size_t)(qw + ql) * 32;
    const float* fsr = fs + (size_t)(qw + ql) * 32;
#pragma unroll
    for (int dk = 0; dk < 4; ++dk) {
      uint4 v = *reinterpret_cast<const uint4*>(qrow + dk * 16 + hi * 8);
      float4 c4 = *reinterpret_cast<const float4*>(fcr + dk * 8 + hi * 4);
      float4 s4 = *reinterpret_cast<const float4*>(fsr + dk * 8 + hi * 4);
      float cc[4] = {c4.x, c4.y, c4.z, c4.w};
      float ss[4] = {s4.x, s4.y, s4.z, s4.w};
      unsigned wd[4] = {v.x, v.y, v.z, v.w};
      u32x4 o;
#pragma unroll
      for (int k2 = 0; k2 < 4; ++k2) {
        float te = bf2f((unsigned short)(wd[k2] & 0xffff));
        float to = bf2f((unsigned short)(wd[k2] >> 16));
        o[k2] = cvtpk((te * cc[k2] - to * ss[k2]) * CLOG_,
                      (te * ss[k2] + to * cc[k2]) * CLOG_);
      }
      qf[dk] = __builtin_bit_cast(bf16x8, o);
    }
  }

  const unsigned short* Kg = K + (size_t)b * L_ * KVD_ + kv * HD_;
  const unsigned short* Vg = Vt + ((size_t)(b * NKV_ + kv)) * HD_ * L_;

  f32x16 oacc0 = {}, oacc1 = {};
  float lrow = 0.f;                     // lane-local partial (combined at end)
  const int rsw = (ql & 7) << 4;

  auto STAGE = [&](int buf, int t) {
    const int k0 = t * 64;
#pragma unroll
    for (int p = 0; p < 2; ++p) {
      int off = (p * 256 + tid) * 16;
      int row = off >> 7;
      int colb = (off & 127) ^ ((row & 7) << 4);
      GLDS16((const char*)Kg + ((size_t)(k0 + row)) * (KVD_ * 2) + colb,
             (char*)Ks[buf] + off);
      GLDS16((const char*)Vg + ((size_t)row) * (L_ * 2) + (size_t)k0 * 2 + colb,
             (char*)Vs[buf] + off);
    }
  };

  int cur = 0;
  STAGE(0, 0);

  for (int t = 0; t < nkt; ++t) {
    asm volatile("s_waitcnt vmcnt(0)" ::: "memory");    // tile-t loads landed (own)
    __builtin_amdgcn_s_barrier();                        // all landed; old buf free
    __builtin_amdgcn_sched_barrier(0);
    if (t + 1 < nkt) STAGE(cur ^ 1, t + 1);              // into just-freed buffer
    const int k0 = t * 64;
    if (k0 < qw + 32) {
      const char* Kl = (const char*)Ks[cur];
      const char* Vl = (const char*)Vs[cur];
      f32x16 s0 = {}, s1 = {};
      __builtin_amdgcn_s_setprio(1);
#pragma unroll
      for (int dk = 0; dk < 4; ++dk) {
        bf16x8 kf0 = *reinterpret_cast<const bf16x8*>(Kl + ql * 128 + ((dk * 32 + hi * 16) ^ rsw));
        bf16x8 kf1 = *reinterpret_cast<const bf16x8*>(Kl + (32 + ql) * 128 + ((dk * 32 + hi * 16) ^ rsw));
        s0 = __builtin_amdgcn_mfma_f32_32x32x16_bf16(kf0, qf[dk], s0, 0, 0, 0);
        s1 = __builtin_amdgcn_mfma_f32_32x32x16_bf16(kf1, qf[dk], s1, 0, 0, 0);
      }
      __builtin_amdgcn_s_setprio(0);
      float p[32];
      float ps = 0.f;
      if (k0 + 63 > qw) {
        int q = qw + ql;
#pragma unroll
        for (int i = 0; i < 32; ++i) {
          float sv = (i < 16) ? s0[i] : s1[i - 16];
          int kk = k0 + (i >> 4) * 32 + (i & 3) + 8 * ((i & 15) >> 2) + 4 * hi;
          float e = exp2f(sv);
          e = (kk > q) ? 0.f : e;
          p[i] = e; ps += e;
        }
      } else {
#pragma unroll
        for (int i = 0; i < 32; ++i) {
          float sv = (i < 16) ? s0[i] : s1[i - 16];
          p[i] = exp2f(sv); ps += p[i];
        }
      }
      lrow += ps;                       // lane-local; no per-tile exchange
      bf16x8 pf[4];
#pragma unroll
      for (int s = 0; s < 4; ++s) {
        int bp = ((s >> 1) << 4) + ((s & 1) << 3);
        unsigned w0 = cvtpk(p[bp + 0], p[bp + 1]);
        unsigned w1 = cvtpk(p[bp + 2], p[bp + 3]);
        unsigned w2 = cvtpk(p[bp + 4], p[bp + 5]);
        unsigned w3 = cvtpk(p[bp + 6], p[bp + 7]);
        plswap2(w0, w2, hi);            // w0=[w0lo|w2lo], w2=[w0hi|w2hi]
        plswap2(w1, w3, hi);
        u32x4 fw;
        fw[0] = w0; fw[1] = w1; fw[2] = w2; fw[3] = w3;
        pf[s] = __builtin_bit_cast(bf16x8, fw);
      }
      __builtin_amdgcn_s_setprio(1);
#pragma unroll
      for (int s = 0; s < 4; ++s) {
        bf16x8 v0 = *reinterpret_cast<const bf16x8*>(Vl + ql * 128 + ((s * 32 + hi * 16) ^ rsw));
        bf16x8 v1 = *reinterpret_cast<const bf16x8*>(Vl + (32 + ql) * 128 + ((s * 32 + hi * 16) ^ rsw));
        oacc0 = __builtin_amdgcn_mfma_f32_32x32x16_bf16(v0, pf[s], oacc0, 0, 0, 0);
        oacc1 = __builtin_amdgcn_mfma_f32_32x32x16_bf16(v1, pf[s], oacc1, 0, 0, 0);
      }
      __builtin_amdgcn_s_setprio(0);
    }
    asm volatile("s_waitcnt lgkmcnt(0)" ::: "memory");   // own reads drained
    cur ^= 1;
  }

  // ---- combine lane-local lrow across halves (one permlane), normalize
  unsigned la = __float_as_uint(lrow), lb = __float_as_uint(lrow);
  plswap2(la, lb, hi);
  float ltot = __uint_as_float(la) + __uint_as_float(lb);
  float inv = 1.f / ltot;
  unsigned short* obase = AO + ((size_t)(b * L_ + qw + ql)) * DIM_ + h * HD_;
#pragma unroll
  for (int g4 = 0; g4 < 4; ++g4) {
    uint2 u;
    u.x = cvtpk(oacc0[g4 * 4 + 0] * inv, oacc0[g4 * 4 + 1] * inv);
    u.y = cvtpk(oacc0[g4 * 4 + 2] * inv, oacc0[g4 * 4 + 3] * inv);
    *reinterpret_cast<uint2*>(obase + g4 * 8 + hi * 4) = u;
    uint2 v;
    v.x = cvtpk(oacc1[g4 * 4 + 0] * inv, oacc1[g4 * 4 + 1] * inv);
    v.y = cvtpk(oacc1[g4 * 4 + 2] * inv, oacc1[g4 * 4 + 3] * inv);
    *reinterpret_cast<uint2*>(obase + 32 + g4 * 8 + hi * 4) = v;
  }
}

extern "C" void kernel_launch(void* const* d_in, const int* in_sizes, int n_in,
                              void* d_out, int out_size, void* d_ws, size_t ws_size,
                              hipStream_t stream) {
  const float* x  = (const float*)d_in[0];
  const float* wq = (const float*)d_in[1];
  const float* wk = (const float*)d_in[2];
  const float* wv = (const float*)d_in[3];
  const float* wo = (const float*)d_in[4];
  const float* fc = (const float*)d_in[5];
  const float* fs = (const float*)d_in[6];
  float* out = (float*)d_out;

  unsigned short* ws  = (unsigned short*)d_ws;
  unsigned short* xb  = ws;                 // 8388608
  unsigned short* wqb = xb  + 8388608;      // 4194304
  unsigned short* wkb = wqb + 4194304;      // 1048576
  unsigned short* wvb = wkb + 1048576;      // 1048576
  unsigned short* wob = wvb + 1048576;      // 4194304
  unsigned short* Qb  = wob + 4194304;      // 8388608 (raw; rope fused in attn)
  unsigned short* Kb  = Qb  + 8388608;      // 2097152 (roped in gemm_qkv epilogue)
  unsigned short* Vtb = Kb  + 2097152;      // 2097152 (V written transposed)
  unsigned short* AOb = Vtb + 2097152;      // 8388608

  cvt_all<<<18432, 256, 0, stream>>>(x, wq, wk, wv, wo, xb, wqb, wkb, wvb, wob);

  gemm_qkv<<<dim3(24, 32), 256, 0, stream>>>(xb, wqb, wkb, wvb, Qb, Kb, Vtb, fc, fs);

  attn_kernel<<<1024, 256, 0, stream>>>(Qb, Kb, Vtb, fc, fs, AOb);

  gemm_bt<1><<<dim3(16, 32), 256, 0, stream>>>(AOb, wob, out, 4096, 2048, 2048);
}

// Round 18
// 212.265 us; speedup vs baseline: 1.1109x; 1.1109x over previous
//
#include <hip/hip_runtime.h>
#include <hip/hip_bf16.h>
#include <stdint.h>

typedef __attribute__((ext_vector_type(8))) short bf16x8;
typedef __attribute__((ext_vector_type(4))) float f32x4;
typedef __attribute__((ext_vector_type(16))) float f32x16;
typedef __attribute__((ext_vector_type(4))) unsigned int u32x4;

#define B_    2
#define L_    2048
#define DIM_  2048
#define NH_   32
#define NKV_  8
#define HD_   64
#define KVD_  512          // NKV_*HD_
#define CLOG_ 0.1803368801111244f   // SCALE * log2(e), folded into Q in attn prologue

__device__ __forceinline__ unsigned short f2bf(float f) {
  unsigned u = __float_as_uint(f);
  u += 0x7fff + ((u >> 16) & 1);          // round-to-nearest-even
  return (unsigned short)(u >> 16);
}
// hw packed f32->bf16 (RNE), 1 VALU op
__device__ __forceinline__ unsigned cvtpk(float lo, float hi_) {
  unsigned r;
  asm("v_cvt_pk_bf16_f32 %0, %1, %2" : "=v"(r) : "v"(lo), "v"(hi_));
  return r;
}
__device__ __forceinline__ float bf2f(unsigned short h) {
  return __uint_as_float(((unsigned)h) << 16);
}
// v_permlane32_swap_b32: a' = [a_lo | b_lo], b' = [a_hi | b_hi]
__device__ __forceinline__ void plswap2(unsigned &a, unsigned &b, int hi) {
#if __has_builtin(__builtin_amdgcn_permlane32_swap)
  auto r = __builtin_amdgcn_permlane32_swap(a, b, false, false);
  a = (unsigned)r[0]; b = (unsigned)r[1];
#else
  unsigned xa = (unsigned)__shfl_xor((int)a, 32);
  unsigned xb = (unsigned)__shfl_xor((int)b, 32);
  unsigned na = hi ? xb : a, nb = hi ? b : xa;
  a = na; b = nb;
#endif
}

#define GLDS16(gsrc, ldst) __builtin_amdgcn_global_load_lds( \
    (const __attribute__((address_space(1))) unsigned int*)(gsrc), \
    (__attribute__((address_space(3))) unsigned int*)(ldst), 16, 0, 0)

// ---------------- fused f32 -> bf16 convert of all 5 tensors ----------------
__global__ void cvt_all(const float* __restrict__ x,  const float* __restrict__ wq,
                        const float* __restrict__ wk, const float* __restrict__ wv,
                        const float* __restrict__ wo,
                        unsigned short* __restrict__ xb,  unsigned short* __restrict__ wqb,
                        unsigned short* __restrict__ wkb, unsigned short* __restrict__ wvb,
                        unsigned short* __restrict__ wob) {
  int i = blockIdx.x * blockDim.x + threadIdx.x;
  const float* src; unsigned short* dst; int off;
  if (i < 2097152)      { src = x;  dst = xb;  off = i; }
  else if (i < 3145728) { src = wq; dst = wqb; off = i - 2097152; }
  else if (i < 3407872) { src = wk; dst = wkb; off = i - 3145728; }
  else if (i < 3670016) { src = wv; dst = wvb; off = i - 3407872; }
  else                  { src = wo; dst = wob; off = i - 3670016; }
  float4 v = reinterpret_cast<const float4*>(src)[off];
  ushort4 o;
  o.x = f2bf(v.x); o.y = f2bf(v.y); o.z = f2bf(v.z); o.w = f2bf(v.w);
  reinterpret_cast<ushort4*>(dst)[off] = o;
}

// ===== 128x128 GEMM core: counted-vmcnt double-buffer, BK=32 (32 KB LDS) ====
// Round-15 verified best (total 212.6). Per K-tile: STAGE(next: 4 gload_lds);
// vmcnt(4); s_barrier; 8 swizzled ds_read_b128 + 16 MFMA (setprio); lgkmcnt(0);
// s_barrier. 64-byte rows: swizzle slot g ^= (row>>1)&3 (16B slots; 2-way
// bank aliasing = free), same involution on staging source and ds_read.
// OUTMODE: 0 = bf16 C[M,N], 1 = f32 C[M,N], 2 = V-transposed Vt[B,KV,D,L]
template<int OUTMODE>
__device__ __forceinline__ void gemm128_core(
    const unsigned short* __restrict__ A,
    const unsigned short* __restrict__ W,
    void* __restrict__ C, int N, int K, int m0, int n0,
    unsigned short (*As)[128 * 32], unsigned short (*Bs)[128 * 32])
{
  const int tid = threadIdx.x;
  const int lane = tid & 63, wid = tid >> 6;
  const int wm = wid >> 1, wn = wid & 1;
  const int r = lane & 15, g = lane >> 4;
  f32x4 acc[4][4] = {};

  auto STAGE = [&](int buf, int k0) {
#pragma unroll
    for (int p = 0; p < 2; ++p) {
      int off = (p * 256 + tid) * 16;              // 0..8191
      int row = off >> 6;                          // 0..127
      int colb = (off & 63) ^ (((row >> 1) & 3) << 4);   // inverse-swizzled src
      GLDS16((const char*)A + ((size_t)(m0 + row) * K + k0) * 2 + colb,
             (char*)As[buf] + off);
      GLDS16((const char*)W + ((size_t)(n0 + row) * K + k0) * 2 + colb,
             (char*)Bs[buf] + off);
    }
  };

  const int nt = K >> 5;
  STAGE(0, 0);
  asm volatile("s_waitcnt vmcnt(0)" ::: "memory");
  __builtin_amdgcn_s_barrier();
  int cur = 0;
  for (int kt = 0; kt < nt; ++kt) {
    if (kt + 1 < nt) {
      STAGE(cur ^ 1, (kt + 1) << 5);
      asm volatile("s_waitcnt vmcnt(4)" ::: "memory");   // prior tile landed
    } else {
      asm volatile("s_waitcnt vmcnt(0)" ::: "memory");
    }
    __builtin_amdgcn_s_barrier();
    __builtin_amdgcn_sched_barrier(0);
    const char* Ab = (const char*)As[cur];
    const char* Bb = (const char*)Bs[cur];
    bf16x8 af[4], bfv[4];
#pragma unroll
    for (int i = 0; i < 4; ++i) {
      int Ra = wm * 64 + i * 16 + r;
      af[i] = *reinterpret_cast<const bf16x8*>(
          Ab + Ra * 64 + ((g ^ ((Ra >> 1) & 3)) << 4));
    }
#pragma unroll
    for (int i = 0; i < 4; ++i) {
      int Rb = wn * 64 + i * 16 + r;
      bfv[i] = *reinterpret_cast<const bf16x8*>(
          Bb + Rb * 64 + ((g ^ ((Rb >> 1) & 3)) << 4));
    }
    __builtin_amdgcn_s_setprio(1);
#pragma unroll
    for (int i = 0; i < 4; ++i)
#pragma unroll
      for (int j = 0; j < 4; ++j)
        acc[i][j] = __builtin_amdgcn_mfma_f32_16x16x32_bf16(af[i], bfv[j], acc[i][j], 0, 0, 0);
    __builtin_amdgcn_s_setprio(0);
    asm volatile("s_waitcnt lgkmcnt(0)" ::: "memory");   // reads done before overwrite
    __builtin_amdgcn_s_barrier();
    cur ^= 1;
  }

  if (OUTMODE == 2) {
#pragma unroll
    for (int i = 0; i < 4; ++i)
#pragma unroll
      for (int jf = 0; jf < 4; ++jf) {
        int col = n0 + wn * 64 + jf * 16 + r;        // 0..511
        int kvi = col >> 6, d = col & 63;
        int tok = m0 + wm * 64 + i * 16 + g * 4;     // 4 consecutive tokens
        int bb = tok >> 11, tl = tok & (L_ - 1);
        uint2 u;
        u.x = cvtpk(acc[i][jf][0], acc[i][jf][1]);
        u.y = cvtpk(acc[i][jf][2], acc[i][jf][3]);
        *reinterpret_cast<uint2*>((unsigned short*)C +
            ((size_t)((bb * NKV_ + kvi) * HD_ + d)) * L_ + tl) = u;
      }
  } else {
#pragma unroll
    for (int i = 0; i < 4; ++i)
#pragma unroll
      for (int jf = 0; jf < 4; ++jf)
#pragma unroll
        for (int j = 0; j < 4; ++j) {
          size_t row = (size_t)(m0 + wm * 64 + i * 16 + g * 4 + j);
          size_t col = (size_t)(n0 + wn * 64 + jf * 16 + r);
          float v = acc[i][jf][j];
          if (OUTMODE == 1) ((float*)C)[row * N + col] = v;
          else ((unsigned short*)C)[row * N + col] = f2bf(v);
        }
  }
}

// ---------------- out-projection / generic GEMM ----------------
template<int OUT_F32>
__global__ __launch_bounds__(256) void gemm_bt(
    const unsigned short* __restrict__ A,
    const unsigned short* __restrict__ W,
    void* __restrict__ C, int M, int N, int K)
{
  __shared__ unsigned short As[2][128 * 32];
  __shared__ unsigned short Bs[2][128 * 32];
  gemm128_core<OUT_F32 ? 1 : 0>(A, W, C, N, K, blockIdx.y * 128, blockIdx.x * 128, As, Bs);
}

// ---------------- fused QKV GEMM (V written TRANSPOSED) ----------------
__global__ __launch_bounds__(256) void gemm_qkv(
    const unsigned short* __restrict__ A,
    const unsigned short* __restrict__ Wq,
    const unsigned short* __restrict__ Wk,
    const unsigned short* __restrict__ Wv,
    unsigned short* __restrict__ Cq,
    unsigned short* __restrict__ Ck,
    unsigned short* __restrict__ Vt)
{
  __shared__ unsigned short As[2][128 * 32];
  __shared__ unsigned short Bs[2][128 * 32];
  const int bx = blockIdx.x;
  const int m0 = blockIdx.y * 128;
  if (bx < 16)
    gemm128_core<0>(A, Wq, Cq, 2048, DIM_, m0, bx * 128, As, Bs);
  else if (bx < 20)
    gemm128_core<0>(A, Wk, Ck, 512, DIM_, m0, (bx - 16) * 128, As, Bs);
  else
    gemm128_core<2>(A, Wv, Vt, 512, DIM_, m0, (bx - 20) * 128, As, Bs);
}

// ---------------- RoPE (K only; Q rope fused into attn), vectorized --------
__global__ void rope_v8(unsigned short* __restrict__ t,
                        const float* __restrict__ fc,
                        const float* __restrict__ fs,
                        int rowElems, int lshift, float scale) {
  int idx = blockIdx.x * blockDim.x + threadIdx.x;
  int row = idx >> lshift;
  if (row >= B_ * L_) return;
  int pos = (idx & ((1 << lshift) - 1)) << 3;   // element offset in row
  int l = row & (L_ - 1);
  int i0 = (pos & 63) >> 1;                     // pair index
  unsigned short* p = t + (size_t)row * rowElems + pos;
  uint4 v = *reinterpret_cast<const uint4*>(p);
  float4 c4 = *reinterpret_cast<const float4*>(fc + l * 32 + i0);
  float4 s4 = *reinterpret_cast<const float4*>(fs + l * 32 + i0);
  float cc[4] = {c4.x * scale, c4.y * scale, c4.z * scale, c4.w * scale};
  float ss[4] = {s4.x * scale, s4.y * scale, s4.z * scale, s4.w * scale};
  unsigned wds[4] = {v.x, v.y, v.z, v.w};
  uint4 o;
  unsigned ow[4];
#pragma unroll
  for (int k = 0; k < 4; ++k) {
    float te = bf2f((unsigned short)(wds[k] & 0xffff));
    float to = bf2f((unsigned short)(wds[k] >> 16));
    ow[k] = cvtpk(te * cc[k] - to * ss[k], te * ss[k] + to * cc[k]);
  }
  o.x = ow[0]; o.y = ow[1]; o.z = ow[2]; o.w = ow[3];
  *reinterpret_cast<uint4*>(p) = o;
}

// ---------------- Flash attention (round-14/15 verified: ~95 us) ------------
// 1D grid, boustrophedon snake chunk mapping; 4 waves x 32 q-rows = 128 q.
// SINGLE barrier per K-tile; Q-RoPE + scale fused into prologue;
// permlane32_swap P exchange; fixed-max log2 softmax; lane-local lrow.
__global__ __launch_bounds__(256) void attn_kernel(
    const unsigned short* __restrict__ Q,
    const unsigned short* __restrict__ K,
    const unsigned short* __restrict__ Vt,
    const float* __restrict__ fc, const float* __restrict__ fs,
    unsigned short* __restrict__ AO)
{
  __shared__ unsigned short Ks[2][64 * 64];
  __shared__ unsigned short Vs[2][64 * 64];
  const int tid = threadIdx.x;
  const int lane = tid & 63, w = tid >> 6;
  const int ql = lane & 31;
  const int hi = lane >> 5;
  const int wid = blockIdx.x;
  const int j = wid >> 6;
  const int blk = j >> 2, pos = j & 3;
  const int base = 15 - 4 * blk;                       // 15,11,7,3
  const int qt = (blk & 1) ? (base - 3 + pos) : (base - pos);
  const int bh = wid & 63;
  const int b = bh >> 5, h = bh & 31, kv = h >> 2;
  const int q0 = qt * 128;
  const int qw = q0 + w * 32;
  const int nkt = (q0 + 128) >> 6;

  // ---- Q fragments with fused RoPE + scale ----
  bf16x8 qf[4];
  {
    const unsigned short* qrow = Q + ((size_t)(b * L_ + qw + ql)) * DIM_ + h * HD_;
    const float* fcr = fc + (size_t)(qw + ql) * 32;
    const float* fsr = fs + (size_t)(qw + ql) * 32;
#pragma unroll
    for (int dk = 0; dk < 4; ++dk) {
      uint4 v = *reinterpret_cast<const uint4*>(qrow + dk * 16 + hi * 8);
      float4 c4 = *reinterpret_cast<const float4*>(fcr + dk * 8 + hi * 4);
      float4 s4 = *reinterpret_cast<const float4*>(fsr + dk * 8 + hi * 4);
      float cc[4] = {c4.x, c4.y, c4.z, c4.w};
      float ss[4] = {s4.x, s4.y, s4.z, s4.w};
      unsigned wd[4] = {v.x, v.y, v.z, v.w};
      u32x4 o;
#pragma unroll
      for (int k2 = 0; k2 < 4; ++k2) {
        float te = bf2f((unsigned short)(wd[k2] & 0xffff));
        float to = bf2f((unsigned short)(wd[k2] >> 16));
        o[k2] = cvtpk((te * cc[k2] - to * ss[k2]) * CLOG_,
                      (te * ss[k2] + to * cc[k2]) * CLOG_);
      }
      qf[dk] = __builtin_bit_cast(bf16x8, o);
    }
  }

  const unsigned short* Kg = K + (size_t)b * L_ * KVD_ + kv * HD_;
  const unsigned short* Vg = Vt + ((size_t)(b * NKV_ + kv)) * HD_ * L_;

  f32x16 oacc0 = {}, oacc1 = {};
  float lrow = 0.f;                     // lane-local partial (combined at end)
  const int rsw = (ql & 7) << 4;

  auto STAGE = [&](int buf, int t) {
    const int k0 = t * 64;
#pragma unroll
    for (int p = 0; p < 2; ++p) {
      int off = (p * 256 + tid) * 16;
      int row = off >> 7;
      int colb = (off & 127) ^ ((row & 7) << 4);
      GLDS16((const char*)Kg + ((size_t)(k0 + row)) * (KVD_ * 2) + colb,
             (char*)Ks[buf] + off);
      GLDS16((const char*)Vg + ((size_t)row) * (L_ * 2) + (size_t)k0 * 2 + colb,
             (char*)Vs[buf] + off);
    }
  };

  int cur = 0;
  STAGE(0, 0);

  for (int t = 0; t < nkt; ++t) {
    asm volatile("s_waitcnt vmcnt(0)" ::: "memory");    // tile-t loads landed (own)
    __builtin_amdgcn_s_barrier();                        // all landed; old buf free
    __builtin_amdgcn_sched_barrier(0);
    if (t + 1 < nkt) STAGE(cur ^ 1, t + 1);              // into just-freed buffer
    const int k0 = t * 64;
    if (k0 < qw + 32) {
      const char* Kl = (const char*)Ks[cur];
      const char* Vl = (const char*)Vs[cur];
      f32x16 s0 = {}, s1 = {};
      __builtin_amdgcn_s_setprio(1);
#pragma unroll
      for (int dk = 0; dk < 4; ++dk) {
        bf16x8 kf0 = *reinterpret_cast<const bf16x8*>(Kl + ql * 128 + ((dk * 32 + hi * 16) ^ rsw));
        bf16x8 kf1 = *reinterpret_cast<const bf16x8*>(Kl + (32 + ql) * 128 + ((dk * 32 + hi * 16) ^ rsw));
        s0 = __builtin_amdgcn_mfma_f32_32x32x16_bf16(kf0, qf[dk], s0, 0, 0, 0);
        s1 = __builtin_amdgcn_mfma_f32_32x32x16_bf16(kf1, qf[dk], s1, 0, 0, 0);
      }
      __builtin_amdgcn_s_setprio(0);
      float p[32];
      float ps = 0.f;
      if (k0 + 63 > qw) {
        int q = qw + ql;
#pragma unroll
        for (int i = 0; i < 32; ++i) {
          float sv = (i < 16) ? s0[i] : s1[i - 16];
          int kk = k0 + (i >> 4) * 32 + (i & 3) + 8 * ((i & 15) >> 2) + 4 * hi;
          float e = exp2f(sv);
          e = (kk > q) ? 0.f : e;
          p[i] = e; ps += e;
        }
      } else {
#pragma unroll
        for (int i = 0; i < 32; ++i) {
          float sv = (i < 16) ? s0[i] : s1[i - 16];
          p[i] = exp2f(sv); ps += p[i];
        }
      }
      lrow += ps;                       // lane-local; no per-tile exchange
      bf16x8 pf[4];
#pragma unroll
      for (int s = 0; s < 4; ++s) {
        int bp = ((s >> 1) << 4) + ((s & 1) << 3);
        unsigned w0 = cvtpk(p[bp + 0], p[bp + 1]);
        unsigned w1 = cvtpk(p[bp + 2], p[bp + 3]);
        unsigned w2 = cvtpk(p[bp + 4], p[bp + 5]);
        unsigned w3 = cvtpk(p[bp + 6], p[bp + 7]);
        plswap2(w0, w2, hi);            // w0=[w0lo|w2lo], w2=[w0hi|w2hi]
        plswap2(w1, w3, hi);
        u32x4 fw;
        fw[0] = w0; fw[1] = w1; fw[2] = w2; fw[3] = w3;
        pf[s] = __builtin_bit_cast(bf16x8, fw);
      }
      __builtin_amdgcn_s_setprio(1);
#pragma unroll
      for (int s = 0; s < 4; ++s) {
        bf16x8 v0 = *reinterpret_cast<const bf16x8*>(Vl + ql * 128 + ((s * 32 + hi * 16) ^ rsw));
        bf16x8 v1 = *reinterpret_cast<const bf16x8*>(Vl + (32 + ql) * 128 + ((s * 32 + hi * 16) ^ rsw));
        oacc0 = __builtin_amdgcn_mfma_f32_32x32x16_bf16(v0, pf[s], oacc0, 0, 0, 0);
        oacc1 = __builtin_amdgcn_mfma_f32_32x32x16_bf16(v1, pf[s], oacc1, 0, 0, 0);
      }
      __builtin_amdgcn_s_setprio(0);
    }
    asm volatile("s_waitcnt lgkmcnt(0)" ::: "memory");   // own reads drained
    cur ^= 1;
  }

  // ---- combine lane-local lrow across halves (one permlane), normalize
  unsigned la = __float_as_uint(lrow), lb = __float_as_uint(lrow);
  plswap2(la, lb, hi);
  float ltot = __uint_as_float(la) + __uint_as_float(lb);
  float inv = 1.f / ltot;
  unsigned short* obase = AO + ((size_t)(b * L_ + qw + ql)) * DIM_ + h * HD_;
#pragma unroll
  for (int g4 = 0; g4 < 4; ++g4) {
    uint2 u;
    u.x = cvtpk(oacc0[g4 * 4 + 0] * inv, oacc0[g4 * 4 + 1] * inv);
    u.y = cvtpk(oacc0[g4 * 4 + 2] * inv, oacc0[g4 * 4 + 3] * inv);
    *reinterpret_cast<uint2*>(obase + g4 * 8 + hi * 4) = u;
    uint2 v;
    v.x = cvtpk(oacc1[g4 * 4 + 0] * inv, oacc1[g4 * 4 + 1] * inv);
    v.y = cvtpk(oacc1[g4 * 4 + 2] * inv, oacc1[g4 * 4 + 3] * inv);
    *reinterpret_cast<uint2*>(obase + 32 + g4 * 8 + hi * 4) = v;
  }
}

extern "C" void kernel_launch(void* const* d_in, const int* in_sizes, int n_in,
                              void* d_out, int out_size, void* d_ws, size_t ws_size,
                              hipStream_t stream) {
  const float* x  = (const float*)d_in[0];
  const float* wq = (const float*)d_in[1];
  const float* wk = (const float*)d_in[2];
  const float* wv = (const float*)d_in[3];
  const float* wo = (const float*)d_in[4];
  const float* fc = (const float*)d_in[5];
  const float* fs = (const float*)d_in[6];
  float* out = (float*)d_out;

  unsigned short* ws  = (unsigned short*)d_ws;
  unsigned short* xb  = ws;                 // 8388608
  unsigned short* wqb = xb  + 8388608;      // 4194304
  unsigned short* wkb = wqb + 4194304;      // 1048576
  unsigned short* wvb = wkb + 1048576;      // 1048576
  unsigned short* wob = wvb + 1048576;      // 4194304
  unsigned short* Qb  = wob + 4194304;      // 8388608 (raw; rope fused in attn)
  unsigned short* Kb  = Qb  + 8388608;      // 2097152
  unsigned short* Vtb = Kb  + 2097152;      // 2097152 (V written transposed)
  unsigned short* AOb = Vtb + 2097152;      // 8388608

  cvt_all<<<18432, 256, 0, stream>>>(x, wq, wk, wv, wo, xb, wqb, wkb, wvb, wob);

  gemm_qkv<<<dim3(24, 32), 256, 0, stream>>>(xb, wqb, wkb, wvb, Qb, Kb, Vtb);

  rope_v8<<<1024, 256, 0, stream>>>(Kb, fc, fs, 512, 6, 1.0f);

  attn_kernel<<<1024, 256, 0, stream>>>(Qb, Kb, Vtb, fc, fs, AOb);

  gemm_bt<1><<<dim3(16, 32), 256, 0, stream>>>(AOb, wob, out, 4096, 2048, 2048);
}